// Round 6
// baseline (135.807 us; speedup 1.0000x reference)
//
#include <hip/hip_runtime.h>
#include <hip/hip_bf16.h>
#include <cstdint>

// DenseMRConv: out = concat([x, max_k(x[idx[n,k]] - x[n])]) @ W + b
// N=100000, K=32, d=64, d_out=64.
//
// R6: (a) 8-deep explicit gather batches + bfrag load moved after Phase A
// (R5's VGPR_Count=36 showed only ~2-3 loads were in flight; launch_bounds
// (256,6) gives the allocator room for 8). (b) gather copy stores bf16(x+8):
// all-positive values make u16 ordering == bf16 ordering, so the 32-deep max
// runs on v_pk_max_u16 (1 op per 2 elems; unpack+max chain gone). Bias
// cancels exactly in the fp32 subtract vs bf16(x_i+8). (c) eis stride 34
// kills the 4-way index-read bank conflict (was stride 32).

typedef __attribute__((ext_vector_type(8))) short short8;
typedef __attribute__((ext_vector_type(4))) float f4;

#define TILE 16
#define ROWS 168   // padded h row stride in bf16 elems (336 B, 16B-aligned)
#define EIS  34    // padded index row stride (ints)
#define BIAS 8.0f

__device__ __forceinline__ unsigned short f2bf(float f) {
  unsigned int u = __builtin_bit_cast(unsigned int, f);
  u += 0x7fffu + ((u >> 16) & 1u);          // round-to-nearest-even
  return (unsigned short)(u >> 16);
}
__device__ __forceinline__ unsigned int pack2(float a, float b) {
  return (unsigned int)f2bf(a) | ((unsigned int)f2bf(b) << 16);
}
__device__ __forceinline__ float bflo(unsigned int u) {
  return __builtin_bit_cast(float, u << 16);
}
__device__ __forceinline__ float bfhi(unsigned int u) {
  return __builtin_bit_cast(float, u & 0xffff0000u);
}
__device__ __forceinline__ unsigned int pkmax(unsigned int a, unsigned int b) {
  unsigned int d;
  asm("v_pk_max_u16 %0, %1, %2" : "=v"(d) : "v"(a), "v"(b));
  return d;
}

// ---- pass 1: x -> biased bf16 copy (blocks [0,nxb)), W -> B-frags (block nxb)
__global__ __launch_bounds__(256)
void convert_kernel(const float* __restrict__ x, unsigned int* __restrict__ xbfB,
                    const float* __restrict__ W, unsigned short* __restrict__ wf,
                    int n8, int nxb) {
  if ((int)blockIdx.x < nxb) {
    int i = blockIdx.x * 256 + threadIdx.x;
    if (i >= n8) return;
    const f4* p = (const f4*)x + (size_t)i * 2;
    f4 a = p[0], b = p[1];
    uint4 w;
    w.x = pack2(a.x + BIAS, a.y + BIAS); w.y = pack2(a.z + BIAS, a.w + BIAS);
    w.z = pack2(b.x + BIAS, b.y + BIAS); w.w = pack2(b.z + BIAS, b.w + BIAS);
    ((uint4*)xbfB)[i] = w;
  } else {
    // B layout for mfma_f32_16x16x32_bf16: lane holds B[k=(l>>4)*8+j][n=l&15].
    #pragma unroll
    for (int q = 0; q < 4; ++q) {
      int idx = threadIdx.x * 4 + q;
      int wv = idx >> 8, ks = (idx >> 6) & 3, l = idx & 63;
      int c = l & 15, g = l >> 4;
      short8 v;
      #pragma unroll
      for (int j = 0; j < 8; ++j)
        v[j] = (short)f2bf(W[(ks * 32 + g * 8 + j) * 64 + wv * 16 + c]);
      *(short8*)(wf + (size_t)idx * 8) = v;
    }
  }
}

// ---- pass 2: gather + packed-max + MFMA GEMM. One block per 16-node tile.
__global__ __launch_bounds__(256, 6)
void mrconv4_kernel(const float* __restrict__ x,
                    const unsigned int* __restrict__ xbfB,  // bf16(x+8), 2/uint
                    const unsigned short* __restrict__ wf,  // prebuilt B-frags
                    const int* __restrict__ ei,
                    const float* __restrict__ bias,
                    float* __restrict__ out,
                    int n_tiles)
{
  __shared__ __align__(16) unsigned short hs[TILE * ROWS];
  __shared__ __align__(16) int eis[TILE * EIS];
  __shared__ __align__(16) float otile[TILE * 64];

  const int tid  = threadIdx.x;
  const int wv   = tid >> 6;
  const int lane = tid & 63;
  const int c = lane & 15;         // MFMA col / m-row selector
  const int g = lane >> 4;         // MFMA quad group
  const int t2 = lane >> 4;        // which of this wave's 4 nodes
  const int h  = (lane >> 3) & 1;  // neighbor half (16 each)
  const int e  = lane & 7;         // 16B feature chunk

  const int node0 = blockIdx.x * TILE;
  const int t = wv * 4 + t2;       // node row within tile

  // ---- stage this tile's 512 indices into padded LDS rows
  {
    int row = tid >> 4;            // 0..15
    int col = (tid & 15) * 2;      // even
    *(int2*)&eis[row * EIS + col] = *(const int2*)(ei + (size_t)node0 * 32 + tid * 2);
  }
  __syncthreads();

  // ---- Phase A: packed u16 max over 16 gathered rows/lane, 8 in flight.
  const unsigned int* gbase = xbfB + e * 4;  // lane-constant chunk offset
  const int ebase = t * EIS + h;
  uint4 macc = {0u, 0u, 0u, 0u};             // u16 0 < all positive bf16
  #pragma unroll
  for (int half = 0; half < 2; ++half) {
    uint4 r[8];
    #pragma unroll
    for (int i = 0; i < 8; ++i) {
      const int j = eis[ebase + half * 16 + i * 2];
      r[i] = *(const uint4*)(gbase + (size_t)j * 32);
    }
    #pragma unroll
    for (int i = 0; i < 8; ++i) {
      macc.x = pkmax(macc.x, r[i].x);
      macc.y = pkmax(macc.y, r[i].y);
      macc.z = pkmax(macc.z, r[i].z);
      macc.w = pkmax(macc.w, r[i].w);
    }
  }

  // ---- B fragments: issue now so they fly during reduce/store/sync.
  short8 bfrag[4];
  #pragma unroll
  for (int ks = 0; ks < 4; ++ks)
    bfrag[ks] = *(const short8*)(wf + (size_t)((wv * 4 + ks) * 64 + lane) * 8);

  // reduce the h-pair (lane bit 3) in packed domain
  macc.x = pkmax(macc.x, __shfl_xor(macc.x, 8));
  macc.y = pkmax(macc.y, __shfl_xor(macc.y, 8));
  macc.z = pkmax(macc.z, __shfl_xor(macc.z, 8));
  macc.w = pkmax(macc.w, __shfl_xor(macc.w, 8));

  if (h == 0) {
    // diff half: (max_j bf16(x_j+8)) - bf16(x_i+8)  -> bias cancels exactly
    const uint4 xrb = *(const uint4*)(xbfB + (size_t)(node0 + t) * 32 + e * 4);
    uint4 w;
    w.x = pack2(bflo(macc.x) - bflo(xrb.x), bfhi(macc.x) - bfhi(xrb.x));
    w.y = pack2(bflo(macc.y) - bflo(xrb.y), bfhi(macc.y) - bfhi(xrb.y));
    w.z = pack2(bflo(macc.z) - bflo(xrb.z), bfhi(macc.z) - bfhi(xrb.z));
    w.w = pack2(bflo(macc.w) - bflo(xrb.w), bfhi(macc.w) - bfhi(xrb.w));
    *(uint4*)(hs + t * ROWS + 64 + e * 8) = w;
  } else {
    // x half: exact bf16(x) from fp32 source (coalesced)
    const f4 xa = *(const f4*)(x + (size_t)(node0 + t) * 64 + e * 8);
    const f4 xb = *(const f4*)(x + (size_t)(node0 + t) * 64 + e * 8 + 4);
    uint4 w;
    w.x = pack2(xa.x, xa.y); w.y = pack2(xa.z, xa.w);
    w.z = pack2(xb.x, xb.y); w.w = pack2(xb.z, xb.w);
    *(uint4*)(hs + t * ROWS + e * 8) = w;
  }
  __syncthreads();

  // ---- Phase B: wave wv computes C[:, wv*16 : wv*16+16] via 4 MFMAs.
  f4 acc = {0.f, 0.f, 0.f, 0.f};
  #pragma unroll
  for (int ks = 0; ks < 4; ++ks) {
    // A layout: lane holds A[m=l&15][k=(l>>4)*8+j]
    short8 a = *(const short8*)(hs + c * ROWS + ks * 32 + g * 8);
    acc = __builtin_amdgcn_mfma_f32_16x16x32_bf16(a, bfrag[ks], acc, 0, 0, 0);
  }

  // ---- Epilogue: C layout col=lane&15, row=(lane>>4)*4+reg [m89-verified].
  const float bb = bias[wv * 16 + c];
  #pragma unroll
  for (int j = 0; j < 4; ++j)
    otile[(g * 4 + j) * 64 + wv * 16 + c] = acc[j] + bb;
  __syncthreads();
  *(f4*)(out + (size_t)node0 * 64 + tid * 4) = *(const f4*)&otile[tid * 4];
}

// ---- fallback (ws too small): R2's proven fp32 kernel
#define FWPB 4
#define FROWS 160
__global__ __launch_bounds__(256, 4)
void mrconv_fp32_kernel(const float* __restrict__ x,
                        const int* __restrict__ ei,
                        const float* __restrict__ W,
                        const float* __restrict__ bias,
                        float* __restrict__ out,
                        int n_tiles)
{
  __shared__ __align__(16) unsigned short hsf[FWPB][TILE * FROWS];
  const int wave = threadIdx.x >> 6;
  const int lane = threadIdx.x & 63;
  const int c = lane & 15;
  const int g = lane >> 4;

  short8 bfrag[4][4];
  #pragma unroll
  for (int ks = 0; ks < 4; ++ks) {
    #pragma unroll
    for (int nt = 0; nt < 4; ++nt) {
      short8 v;
      #pragma unroll
      for (int j = 0; j < 8; ++j) {
        int k = ks * 32 + g * 8 + j;
        v[j] = (short)f2bf(W[k * 64 + nt * 16 + c]);
      }
      bfrag[ks][nt] = v;
    }
  }

  const int tile = blockIdx.x * FWPB + wave;
  if (tile >= n_tiles) return;
  const int node0 = tile * TILE;
  unsigned short* hrow = &hsf[wave][0];

  #pragma unroll 2
  for (int t = 0; t < TILE; ++t) {
    const int n = node0 + t;
    const f4 xi = *(const f4*)(x + (size_t)n * 64 + 4 * c);
    f4 m = { -3.4e38f, -3.4e38f, -3.4e38f, -3.4e38f };
    #pragma unroll
    for (int it = 0; it < 8; ++it) {
      const int j = ei[(size_t)n * 32 + it * 4 + g];
      const f4 xj = *(const f4*)(x + (size_t)j * 64 + 4 * c);
      m.x = fmaxf(m.x, xj.x - xi.x);
      m.y = fmaxf(m.y, xj.y - xi.y);
      m.z = fmaxf(m.z, xj.z - xi.z);
      m.w = fmaxf(m.w, xj.w - xi.w);
    }
    m.x = fmaxf(m.x, __shfl_xor(m.x, 16));
    m.y = fmaxf(m.y, __shfl_xor(m.y, 16));
    m.z = fmaxf(m.z, __shfl_xor(m.z, 16));
    m.w = fmaxf(m.w, __shfl_xor(m.w, 16));
    m.x = fmaxf(m.x, __shfl_xor(m.x, 32));
    m.y = fmaxf(m.y, __shfl_xor(m.y, 32));
    m.z = fmaxf(m.z, __shfl_xor(m.z, 32));
    m.w = fmaxf(m.w, __shfl_xor(m.w, 32));
    if (g == 0) {
      ushort4 p;
      p.x = f2bf(xi.x); p.y = f2bf(xi.y); p.z = f2bf(xi.z); p.w = f2bf(xi.w);
      *(ushort4*)(hrow + t * FROWS + 4 * c) = p;
    } else if (g == 1) {
      ushort4 p;
      p.x = f2bf(m.x); p.y = f2bf(m.y); p.z = f2bf(m.z); p.w = f2bf(m.w);
      *(ushort4*)(hrow + t * FROWS + 64 + 4 * c) = p;
    }
  }
  __asm__ volatile("s_waitcnt lgkmcnt(0)" ::: "memory");

  f4 acc[4] = {{0.f,0.f,0.f,0.f},{0.f,0.f,0.f,0.f},{0.f,0.f,0.f,0.f},{0.f,0.f,0.f,0.f}};
  #pragma unroll
  for (int ks = 0; ks < 4; ++ks) {
    short8 a = *(const short8*)(hrow + c * FROWS + ks * 32 + g * 8);
    #pragma unroll
    for (int nt = 0; nt < 4; ++nt)
      acc[nt] = __builtin_amdgcn_mfma_f32_16x16x32_bf16(a, bfrag[ks][nt], acc[nt], 0, 0, 0);
  }
  const int rbase = node0 + g * 4;
  #pragma unroll
  for (int nt = 0; nt < 4; ++nt) {
    const float bb = bias[nt * 16 + c];
    #pragma unroll
    for (int j = 0; j < 4; ++j)
      out[(size_t)(rbase + j) * 64 + nt * 16 + c] = acc[nt][j] + bb;
  }
}

extern "C" void kernel_launch(void* const* d_in, const int* in_sizes, int n_in,
                              void* d_out, int out_size, void* d_ws, size_t ws_size,
                              hipStream_t stream) {
  const float* x  = (const float*)d_in[0];
  const int*   ei = (const int*)d_in[1];     // int64 in reference -> int32 here
  const float* W  = (const float*)d_in[2];
  const float* b  = (const float*)d_in[3];
  float* out = (float*)d_out;

  const int N = in_sizes[0] / 64;            // 100000
  const int n_tiles = N / TILE;              // 6250

  const size_t xbf_bytes = (size_t)N * 64 * 2;   // 12.8 MB
  const size_t wf_bytes  = 1024 * 16;            // 16 KB of B-frags
  if (ws_size >= xbf_bytes + wf_bytes) {
    unsigned int*   xbfB = (unsigned int*)d_ws;
    unsigned short* wf   = (unsigned short*)((char*)d_ws + xbf_bytes);
    const int n8  = N * 64 / 8;                  // 800000
    const int nxb = (n8 + 255) / 256;            // 3125
    hipLaunchKernelGGL(convert_kernel, dim3(nxb + 1), dim3(256), 0, stream,
                       x, xbfB, W, wf, n8, nxb);
    hipLaunchKernelGGL(mrconv4_kernel, dim3(n_tiles), dim3(256), 0, stream,
                       x, xbfB, wf, ei, b, out, n_tiles);
  } else {
    const int blocks = (n_tiles + FWPB - 1) / FWPB;
    hipLaunchKernelGGL(mrconv_fp32_kernel, dim3(blocks), dim3(256), 0, stream,
                       x, ei, W, b, out, n_tiles);
  }
}